// Round 9
// baseline (769.822 us; speedup 1.0000x reference)
//
#include <hip/hip_runtime.h>
#include <hip/hip_bf16.h>
#include <hip/hip_fp16.h>
#include <math.h>

#define N_NODES 50000
#define N_EDGES 800000
#define NHEADS  4
#define NEG_SLOPE 0.2f

typedef __attribute__((ext_vector_type(8))) _Float16 half8v;
typedef __attribute__((ext_vector_type(4))) float f32x4;

__device__ __forceinline__ void gld_lds16(const ushort* g, ushort* l) {
  __builtin_amdgcn_global_load_lds(
      (const __attribute__((address_space(1))) void*)g,
      (__attribute__((address_space(3))) void*)l, 16, 0, 0);
}

// ---------------------------------------------------------------------------
// fused: fp32->fp16 cast of x  +  split/transpose of all 3 weight matrices
// ---------------------------------------------------------------------------
__global__ void cast_all_kernel(const float* __restrict__ x, __half* __restrict__ x16,
                                const float* __restrict__ W0,
                                const float* __restrict__ W1,
                                const float* __restrict__ W2,
                                __half* __restrict__ B0h, __half* __restrict__ B0l,
                                __half* __restrict__ B1h, __half* __restrict__ B1l,
                                __half* __restrict__ B2h, __half* __restrict__ B2l) {
  int b = blockIdx.x;
  if (b < 6250) {
    int i = b * 256 + threadIdx.x;
    float4 v = ((const float4*)x)[i];
    __half2 a = __floats2half2_rn(v.x, v.y);
    __half2 c = __floats2half2_rn(v.z, v.w);
    ((__half2*)x16)[2 * i] = a;
    ((__half2*)x16)[2 * i + 1] = c;
  } else {
    int i = (b - 6250) * 256 + threadIdx.x;
    if (i >= 229376) return;
    const float* W;
    __half *bh, *bl;
    int kshift, N, base;
    if (i < 32768)       { W = W0; bh = B0h; bl = B0l; kshift = 7; N = 256; base = 0; }
    else if (i < 98304)  { W = W1; bh = B1h; bl = B1l; kshift = 8; N = 256; base = 32768; }
    else                 { W = W2; bh = B2h; bl = B2l; kshift = 8; N = 512; base = 98304; }
    int j = i - base;
    int K = 1 << kshift;
    int nn = j >> kshift, k = j & (K - 1);
    float v = W[(size_t)k * N + nn];
    __half h = __float2half(v);
    bh[j] = h;
    bl[j] = __float2half(v - __half2float(h));
  }
}

// ---------------------------------------------------------------------------
// fp16 split-B MFMA GEMM, 128x128 tile, BK=32, LDS-staged (24 KB).
// ---------------------------------------------------------------------------
__global__ __launch_bounds__(256) void gemm_mfma_kernel(
    const __half* __restrict__ Ah, const __half* __restrict__ Bth,
    const __half* __restrict__ Btl, __half* __restrict__ h16,
    const float* __restrict__ asrc, const float* __restrict__ adst,
    float* __restrict__ a_s, float* __restrict__ a_d, int M, int K, int N, int Cph) {
  __shared__ ushort lds[3 * 4096];
  int tid = threadIdx.x;
  int lane = tid & 63, w = tid >> 6;
  int wm = w >> 1, wn = w & 1;
  int r16 = lane & 15, kgrp = lane >> 4;
  int bm = blockIdx.y * 128, bn = blockIdx.x * 128;

  const ushort* gp[6];
#pragma unroll
  for (int i = 0; i < 6; ++i) {
    int c = i * 256 + tid;
    int mmat = c >> 9;
    int s = c & 511;
    int row = s >> 2;
    int kg = (s & 3) ^ ((row >> 1) & 3);
    const ushort* base;
    int rowg;
    if (mmat == 0)      { base = (const ushort*)Ah;  rowg = min(bm + row, M - 1); }
    else if (mmat == 1) { base = (const ushort*)Bth; rowg = bn + row; }
    else                { base = (const ushort*)Btl; rowg = bn + row; }
    gp[i] = base + (size_t)rowg * K + kg * 8;
  }

  f32x4 acc[4][4] = {};
  for (int k0 = 0; k0 < K; k0 += 32) {
#pragma unroll
    for (int i = 0; i < 6; ++i)
      gld_lds16(gp[i] + k0, lds + i * 2048 + tid * 8);
    __syncthreads();
    half8v ah[4], bh[4], bl[4];
#pragma unroll
    for (int m = 0; m < 4; ++m) {
      int row = wm * 64 + m * 16 + r16;
      int s = row * 4 + (kgrp ^ ((row >> 1) & 3));
      ah[m] = *(const half8v*)(lds + 0 * 4096 + s * 8);
    }
#pragma unroll
    for (int j = 0; j < 4; ++j) {
      int row = wn * 64 + j * 16 + r16;
      int s = row * 4 + (kgrp ^ ((row >> 1) & 3));
      bh[j] = *(const half8v*)(lds + 1 * 4096 + s * 8);
      bl[j] = *(const half8v*)(lds + 2 * 4096 + s * 8);
    }
#pragma unroll
    for (int m = 0; m < 4; ++m)
#pragma unroll
      for (int j = 0; j < 4; ++j) {
        acc[m][j] = __builtin_amdgcn_mfma_f32_16x16x32_f16(ah[m], bh[j], acc[m][j], 0, 0, 0);
        acc[m][j] = __builtin_amdgcn_mfma_f32_16x16x32_f16(ah[m], bl[j], acc[m][j], 0, 0, 0);
      }
    __syncthreads();
  }

  int colbase = bn + wn * 64;
  int hd = colbase / Cph;
#pragma unroll
  for (int m = 0; m < 4; ++m) {
#pragma unroll
    for (int r = 0; r < 4; ++r) {
      int row = bm + wm * 64 + m * 16 + kgrp * 4 + r;
      bool ok = row < M;
      float ps = 0.f, pd = 0.f;
#pragma unroll
      for (int j = 0; j < 4; ++j) {
        float val = acc[m][j][r];
        int col = colbase + 16 * j + r16;
        if (ok) h16[(size_t)row * N + col] = __float2half(val);
        ps += val * asrc[col];
        pd += val * adst[col];
      }
#pragma unroll
      for (int o = 8; o >= 1; o >>= 1) {
        ps += __shfl_xor(ps, o);
        pd += __shfl_xor(pd, o);
      }
      if (r16 == 0 && ok) {
        atomicAdd(&a_s[row * NHEADS + hd], ps);
        atomicAdd(&a_d[row * NHEADS + hd], pd);
      }
    }
  }
}

// ---------------------------------------------------------------------------
// fused: edge_attr column sums (blocks 0..511) + degree count (blocks 512+)
// ---------------------------------------------------------------------------
__global__ void prep0_kernel(const float* __restrict__ ea, float* __restrict__ sums,
                             const int* __restrict__ dst, int* __restrict__ deg, int E) {
  int tid = threadIdx.x;
  if (blockIdx.x < 512) {
    int col = tid & 15;
    float s = 0.f;
    for (int r = blockIdx.x * 16 + (tid >> 4); r < E; r += 512 * 16)
      s += ea[(size_t)r * 16 + col];
    __shared__ float red[256];
    red[tid] = s;
    __syncthreads();
    for (int off = 128; off >= 16; off >>= 1) {
      if (tid < off) red[tid] += red[tid + off];
      __syncthreads();
    }
    if (tid < 16) atomicAdd(&sums[tid], red[tid]);
  } else {
    int i = (blockIdx.x - 512) * 256 + tid;
    int s = 2048 * 256;
    for (; i < E; i += s) atomicAdd(&deg[dst[i]], 1);
  }
}

// ---------------------------------------------------------------------------
// wvec + ae_self
// ---------------------------------------------------------------------------
__global__ void wvec_kernel(const float* __restrict__ We0, const float* __restrict__ ae0,
                            const float* __restrict__ We1, const float* __restrict__ ae1,
                            const float* __restrict__ We2, const float* __restrict__ ae2,
                            const float* __restrict__ ea_sum,
                            float* __restrict__ wvec, float* __restrict__ ae_self) {
  __shared__ float sw[192];
  int tid = threadIdx.x;
  if (tid < 192) {
    int l = tid >> 6, rem = tid & 63, k = rem >> 2, hd = rem & 3;
    int C = (l == 2) ? 128 : 64;
    const float* We = (l == 0) ? We0 : (l == 1) ? We1 : We2;
    const float* ae = (l == 0) ? ae0 : (l == 1) ? ae1 : ae2;
    float s = 0.f;
    for (int c = 0; c < C; ++c) s += We[(size_t)k * (4 * C) + hd * C + c] * ae[hd * C + c];
    sw[tid] = s;
    wvec[tid] = s;
  }
  __syncthreads();
  if (tid < 12) {
    int l = tid >> 2, hd = tid & 3;
    const float invE = 1.0f / (float)N_EDGES;
    float s = 0.f;
    for (int k = 0; k < 16; ++k) s += ea_sum[k] * invE * sw[l * 64 + k * 4 + hd];
    ae_self[tid] = s;
  }
}

// ---------------------------------------------------------------------------
// CSR build: hierarchical scan + packed scatter
// ---------------------------------------------------------------------------
__global__ void scan_a_kernel(const int* __restrict__ deg, int* __restrict__ tmp,
                              int* __restrict__ bsum, int n) {
  __shared__ int s[256];
  int i = blockIdx.x * 256 + threadIdx.x;
  int v = (i < n) ? (deg[i] + 1) : 0;
  s[threadIdx.x] = v;
  __syncthreads();
  for (int d = 1; d < 256; d <<= 1) {
    int t = (threadIdx.x >= d) ? s[threadIdx.x - d] : 0;
    __syncthreads();
    s[threadIdx.x] += t;
    __syncthreads();
  }
  if (i < n) tmp[i] = s[threadIdx.x] - v;
  if (threadIdx.x == 255) bsum[blockIdx.x] = s[255];
}
__global__ void scan_b_kernel(int* bsum, int nb) {
  __shared__ int s[256];
  int v = (threadIdx.x < nb) ? bsum[threadIdx.x] : 0;
  s[threadIdx.x] = v;
  __syncthreads();
  for (int d = 1; d < 256; d <<= 1) {
    int t = (threadIdx.x >= d) ? s[threadIdx.x - d] : 0;
    __syncthreads();
    s[threadIdx.x] += t;
    __syncthreads();
  }
  if (threadIdx.x < nb) bsum[threadIdx.x] = s[threadIdx.x] - v;
}
__global__ void scan_c_kernel(const int* __restrict__ tmp, const int* __restrict__ bsum,
                              int* __restrict__ offsets, int* __restrict__ cursor,
                              int n, int tot) {
  int i = blockIdx.x * 256 + threadIdx.x;
  if (i < n) {
    int o = tmp[i] + bsum[blockIdx.x];
    offsets[i] = o;
    cursor[i] = o;
  }
  if (i == 0) offsets[n] = tot;
}
__global__ void scatter_kernel(const int* __restrict__ src, const int* __restrict__ dst,
                               int* cursor, uint2* __restrict__ csr_pack, int E, int n) {
  int i = blockIdx.x * blockDim.x + threadIdx.x;
  int s = gridDim.x * blockDim.x;
  int tot = E + n;
  for (; i < tot; i += s) {
    int ss, dd, eid;
    if (i < E) { ss = src[i]; dd = dst[i]; eid = i; }
    else       { ss = i - E; dd = ss;     eid = E; }
    int pos = atomicAdd(&cursor[dd], 1);
    csr_pack[pos] = make_uint2((uint)ss, (uint)eid);
  }
}

// ---------------------------------------------------------------------------
// a_e in CSR order for all 3 layers + csr_src unpack
// ---------------------------------------------------------------------------
__global__ void ae_csr_kernel(const float* __restrict__ ea, const float* __restrict__ wv,
                              const float* __restrict__ ae_self,
                              const uint2* __restrict__ csr_pack,
                              float* __restrict__ aec, int* __restrict__ csr_src,
                              int tot, int E) {
  int i = blockIdx.x * blockDim.x + threadIdx.x;
  int stride = gridDim.x * blockDim.x;
  for (int p = i; p < tot; p += stride) {
    uint2 pk = csr_pack[p];
    int eid = (int)pk.y;
    csr_src[p] = (int)pk.x;
    if (eid >= E) {
#pragma unroll
      for (int l = 0; l < 3; ++l)
        *(float4*)(aec + ((size_t)l * tot + p) * 4) =
            make_float4(ae_self[l * 4 + 0], ae_self[l * 4 + 1],
                        ae_self[l * 4 + 2], ae_self[l * 4 + 3]);
    } else {
      float row[16];
      const float4* rp = (const float4*)(ea + (size_t)eid * 16);
#pragma unroll
      for (int q = 0; q < 4; ++q) {
        float4 v = rp[q];
        row[q * 4 + 0] = v.x; row[q * 4 + 1] = v.y;
        row[q * 4 + 2] = v.z; row[q * 4 + 3] = v.w;
      }
#pragma unroll
      for (int l = 0; l < 3; ++l) {
        float s0 = 0, s1 = 0, s2 = 0, s3 = 0;
#pragma unroll
        for (int k = 0; k < 16; ++k) {
          float v = row[k];
          s0 += v * wv[l * 64 + k * 4 + 0];
          s1 += v * wv[l * 64 + k * 4 + 1];
          s2 += v * wv[l * 64 + k * 4 + 2];
          s3 += v * wv[l * 64 + k * 4 + 3];
        }
        *(float4*)(aec + ((size_t)l * tot + p) * 4) = make_float4(s0, s1, s2, s3);
      }
    }
  }
}

// ---------------------------------------------------------------------------
// barrier-free aggregation: wave = head, NPB=4 nodes per block.
// All softmax state stays in registers; broadcast via __shfl(reg, t).
// MODE 0 (C=64): lane owns 1 output channel (ch = tid); zero LDS/barriers.
//   -> y16 fp16 (next layer's A), bias+ELU.
// MODE 1 (C=128): lane owns 2 channels of its head; one barrier for the
//   head-mean (NPB==NHEADS: wave g reduces node g). -> fp32 yf.
// ---------------------------------------------------------------------------
template <int MODE>
__global__ __launch_bounds__(256) void aggw_kernel(
    const __half* __restrict__ h, const float* __restrict__ a_s,
    const float* __restrict__ a_d, const float* __restrict__ a_e,
    const int* __restrict__ offsets, const int* __restrict__ csr_src,
    const float* __restrict__ bias, __half* __restrict__ y16,
    float* __restrict__ yf) {
  constexpr int NPB = 4;
  int tid = threadIdx.x;
  int g = tid >> 6, l = tid & 63;
  int nbase = blockIdx.x * NPB;

  int beg[NPB], dg[NPB], sreg[NPB];
  float exreg[NPB], inv[NPB], acc0[NPB], acc1[NPB];

  // ---- stage A: wave-local softmax per node (fast path deg<=64) ----
#pragma unroll
  for (int it = 0; it < NPB; ++it) {
    int nd = nbase + it;
    int b0 = offsets[nd];
    int d = offsets[nd + 1] - b0;
    beg[it] = b0; dg[it] = d;
    sreg[it] = 0; exreg[it] = 0.f; inv[it] = 0.f;
    acc0[it] = 0.f; acc1[it] = 0.f;
    if (d > 64) continue;
    bool valid = l < d;
    int s = 0;
    float al = -1e30f;
    if (valid) {
      int j = b0 + l;
      s = csr_src[j];
      float aev = a_e[(size_t)j * NHEADS + g];
      float v = a_s[s * NHEADS + g] + a_d[nd * NHEADS + g] + aev;
      al = (v > 0.f) ? v : NEG_SLOPE * v;
    }
    float m = al;
#pragma unroll
    for (int o = 32; o >= 1; o >>= 1) m = fmaxf(m, __shfl_xor(m, o));
    float ex = valid ? __expf(al - m) : 0.f;
    float ds = ex;
#pragma unroll
    for (int o = 32; o >= 1; o >>= 1) ds += __shfl_xor(ds, o);
    sreg[it] = s;
    exreg[it] = ex;
    inv[it] = 1.f / (ds + 1e-16f);
  }

  // ---- stage B: gather-accumulate (fast path) ----
#pragma unroll
  for (int it = 0; it < NPB; ++it) {
    int d = dg[it];
    if (d > 64) continue;
    int t = 0;
    for (; t + 3 < d; t += 4) {
      int st0 = __shfl(sreg[it], t),     st1 = __shfl(sreg[it], t + 1);
      int st2 = __shfl(sreg[it], t + 2), st3 = __shfl(sreg[it], t + 3);
      float e0 = __shfl(exreg[it], t),     e1 = __shfl(exreg[it], t + 1);
      float e2 = __shfl(exreg[it], t + 2), e3 = __shfl(exreg[it], t + 3);
      if (MODE == 0) {
        float v0 = __half2float(h[(size_t)st0 * 256 + g * 64 + l]);
        float v1 = __half2float(h[(size_t)st1 * 256 + g * 64 + l]);
        float v2 = __half2float(h[(size_t)st2 * 256 + g * 64 + l]);
        float v3 = __half2float(h[(size_t)st3 * 256 + g * 64 + l]);
        acc0[it] += e0 * v0 + e1 * v1 + e2 * v2 + e3 * v3;
      } else {
        float2 f0 = __half22float2(*(const __half2*)(h + (size_t)st0 * 512 + g * 128 + 2 * l));
        float2 f1 = __half22float2(*(const __half2*)(h + (size_t)st1 * 512 + g * 128 + 2 * l));
        float2 f2 = __half22float2(*(const __half2*)(h + (size_t)st2 * 512 + g * 128 + 2 * l));
        float2 f3 = __half22float2(*(const __half2*)(h + (size_t)st3 * 512 + g * 128 + 2 * l));
        acc0[it] += e0 * f0.x + e1 * f1.x + e2 * f2.x + e3 * f3.x;
        acc1[it] += e0 * f0.y + e1 * f1.y + e2 * f2.y + e3 * f3.y;
      }
    }
    for (; t < d; ++t) {
      int st = __shfl(sreg[it], t);
      float e = __shfl(exreg[it], t);
      if (MODE == 0) {
        acc0[it] += e * __half2float(h[(size_t)st * 256 + g * 64 + l]);
      } else {
        float2 f = __half22float2(*(const __half2*)(h + (size_t)st * 512 + g * 128 + 2 * l));
        acc0[it] += e * f.x;
        acc1[it] += e * f.y;
      }
    }
  }

  // ---- slow path (deg>64), wave-local chunked two-pass ----
#pragma unroll
  for (int it = 0; it < NPB; ++it) {
    if (dg[it] <= 64) continue;
    int nd = nbase + it;
    int b0 = beg[it], end = b0 + dg[it];
    float a_dn = a_d[nd * NHEADS + g];
    float m = -1e30f;
    for (int j0 = b0; j0 < end; j0 += 64) {
      int j = j0 + l;
      if (j < end) {
        int s = csr_src[j];
        float v = a_s[s * NHEADS + g] + a_dn + a_e[(size_t)j * NHEADS + g];
        float al = (v > 0.f) ? v : NEG_SLOPE * v;
        m = fmaxf(m, al);
      }
    }
#pragma unroll
    for (int o = 32; o >= 1; o >>= 1) m = fmaxf(m, __shfl_xor(m, o));
    float dsum = 0.f;
    for (int j0 = b0; j0 < end; j0 += 64) {
      int j = j0 + l;
      int cnt = min(64, end - j0);
      int s = 0;
      float ex = 0.f;
      if (j < end) {
        s = csr_src[j];
        float v = a_s[s * NHEADS + g] + a_dn + a_e[(size_t)j * NHEADS + g];
        float al = (v > 0.f) ? v : NEG_SLOPE * v;
        ex = __expf(al - m);
      }
      dsum += ex;
      for (int t = 0; t < cnt; ++t) {
        int st = __shfl(s, t);
        float e = __shfl(ex, t);
        if (MODE == 0) {
          acc0[it] += e * __half2float(h[(size_t)st * 256 + g * 64 + l]);
        } else {
          float2 f = __half22float2(*(const __half2*)(h + (size_t)st * 512 + g * 128 + 2 * l));
          acc0[it] += e * f.x;
          acc1[it] += e * f.y;
        }
      }
    }
#pragma unroll
    for (int o = 32; o >= 1; o >>= 1) dsum += __shfl_xor(dsum, o);
    inv[it] = 1.f / (dsum + 1e-16f);
  }

  // ---- epilogue ----
  if (MODE == 0) {
    float bval = bias[g * 64 + l];
#pragma unroll
    for (int it = 0; it < NPB; ++it) {
      int nd = nbase + it;
      float o = acc0[it] * inv[it] + bval;
      o = (o > 0.f) ? o : (__expf(o) - 1.f);
      y16[(size_t)nd * 256 + g * 64 + l] = __float2half(o);
    }
  } else {
    __shared__ float2 red[NPB][NHEADS][64];
#pragma unroll
    for (int it = 0; it < NPB; ++it)
      red[it][g][l] = make_float2(acc0[it] * inv[it], acc1[it] * inv[it]);
    __syncthreads();
    // NPB == NHEADS: wave g reduces node (nbase+g)
    int nd = nbase + g;
    float2 s0 = red[g][0][l], s1 = red[g][1][l];
    float2 s2 = red[g][2][l], s3 = red[g][3][l];
    float o0 = (s0.x + s1.x + s2.x + s3.x) * 0.25f + bias[2 * l];
    float o1 = (s0.y + s1.y + s2.y + s3.y) * 0.25f + bias[2 * l + 1];
    *(float2*)(yf + (size_t)nd * 128 + 2 * l) = make_float2(o0, o1);
  }
}

// ---------------------------------------------------------------------------
// global mean pool (segment-batched over sorted batch ids)
// ---------------------------------------------------------------------------
__global__ void pool_kernel(const float* __restrict__ y, const int* __restrict__ batch,
                            float* __restrict__ pool, float* __restrict__ cnt, int n) {
  int n0 = blockIdx.x * 256;
  if (n0 >= n) return;
  int n1 = min(n0 + 256, n);
  int c = threadIdx.x;  // 128 threads
  float accum = 0.f;
  int cur = batch[n0];
  int cn = 0;
  for (int nd = n0; nd < n1; ++nd) {
    int g = batch[nd];
    if (g != cur) {
      atomicAdd(&pool[cur * 128 + c], accum);
      if (c == 0) atomicAdd(&cnt[cur], (float)cn);
      accum = 0.f; cn = 0; cur = g;
    }
    accum += y[(size_t)nd * 128 + c];
    cn++;
  }
  atomicAdd(&pool[cur * 128 + c], accum);
  if (c == 0) atomicAdd(&cnt[cur], (float)cn);
}
__global__ void finalize_kernel(const float* __restrict__ pool,
                                const float* __restrict__ cnt, float* __restrict__ out) {
  int i = blockIdx.x * blockDim.x + threadIdx.x;
  if (i < 64 * 128) out[i] = pool[i] / fmaxf(cnt[i >> 7], 1.f);
}

// ---------------------------------------------------------------------------
extern "C" void kernel_launch(void* const* d_in, const int* in_sizes, int n_in,
                              void* d_out, int out_size, void* d_ws, size_t ws_size,
                              hipStream_t stream) {
  const float* x = (const float*)d_in[0];
  const int* ei = (const int*)d_in[1];
  const float* ea = (const float*)d_in[2];
  const int* batch = (const int*)d_in[3];
  const float* W[3]    = {(const float*)d_in[4],  (const float*)d_in[10], (const float*)d_in[16]};
  const float* asrc[3] = {(const float*)d_in[5],  (const float*)d_in[11], (const float*)d_in[17]};
  const float* adst[3] = {(const float*)d_in[6],  (const float*)d_in[12], (const float*)d_in[18]};
  const float* Wep[3]  = {(const float*)d_in[7],  (const float*)d_in[13], (const float*)d_in[19]};
  const float* aep[3]  = {(const float*)d_in[8],  (const float*)d_in[14], (const float*)d_in[20]};
  const float* bp[3]   = {(const float*)d_in[9],  (const float*)d_in[15], (const float*)d_in[21]};

  char* ws = (char*)d_ws;
  size_t off = 0;
  auto take = [&](size_t bytes) -> void* {
    void* p = ws + off;
    off = (off + bytes + 255) & ~(size_t)255;
    return p;
  };
  const int TOT = N_EDGES + N_NODES;
  size_t zero_begin = off;
  float* ea_sum = (float*)take(16 * 4);
  float* pool   = (float*)take(8192 * 4);
  float* cnt    = (float*)take(64 * 4);
  int*   deg    = (int*)take((size_t)N_NODES * 4);
  float* a_sd   = (float*)take((size_t)3 * 2 * N_NODES * NHEADS * 4);
  size_t zero_bytes = off - zero_begin;

  float* wvec    = (float*)take(192 * 4);
  float* ae_self = (float*)take(12 * 4);
  int* tmp     = (int*)take((size_t)N_NODES * 4);
  int* bsum    = (int*)take(256 * 4);
  int* offsets = (int*)take(((size_t)N_NODES + 1) * 4);
  int* cursor  = (int*)take((size_t)N_NODES * 4);
  uint2* csr_pack = (uint2*)take((size_t)TOT * 8);
  int* csr_src = (int*)take((size_t)TOT * 4);
  float* aec  = (float*)take((size_t)3 * TOT * NHEADS * 4);
  __half* x16 = (__half*)take((size_t)N_NODES * 128 * 2);
  __half* Bh[3], *Bl[3];
  Bh[0] = (__half*)take((size_t)32768 * 2);  Bl[0] = (__half*)take((size_t)32768 * 2);
  Bh[1] = (__half*)take((size_t)65536 * 2);  Bl[1] = (__half*)take((size_t)65536 * 2);
  Bh[2] = (__half*)take((size_t)131072 * 2); Bl[2] = (__half*)take((size_t)131072 * 2);
  __half* h16 = (__half*)take((size_t)N_NODES * 512 * 2);
  __half* y16 = (__half*)take((size_t)N_NODES * 256 * 2);
  float* ybuf = (float*)take((size_t)N_NODES * 128 * 4);

  const int* srcp = ei;
  const int* dstp = ei + N_EDGES;
  const int NB = (N_NODES + 255) / 256;

  hipMemsetAsync(ws + zero_begin, 0, zero_bytes, stream);
  prep0_kernel<<<512 + 2048, 256, 0, stream>>>(ea, ea_sum, dstp, deg, N_EDGES);
  scan_a_kernel<<<NB, 256, 0, stream>>>(deg, tmp, bsum, N_NODES);
  scan_b_kernel<<<1, 256, 0, stream>>>(bsum, NB);
  scan_c_kernel<<<NB, 256, 0, stream>>>(tmp, bsum, offsets, cursor, N_NODES, TOT);
  scatter_kernel<<<2048, 256, 0, stream>>>(srcp, dstp, cursor, csr_pack, N_EDGES, N_NODES);
  wvec_kernel<<<1, 256, 0, stream>>>(Wep[0], aep[0], Wep[1], aep[1], Wep[2], aep[2],
                                     ea_sum, wvec, ae_self);
  ae_csr_kernel<<<2048, 256, 0, stream>>>(ea, wvec, ae_self, csr_pack, aec, csr_src,
                                          TOT, N_EDGES);
  cast_all_kernel<<<6250 + 896, 256, 0, stream>>>(x, x16, W[0], W[1], W[2], Bh[0], Bl[0],
                                                  Bh[1], Bl[1], Bh[2], Bl[2]);

  const __half* Acur = x16;
  const int AGGB = N_NODES / 4;  // 12500, N_NODES % 4 == 0
  for (int l = 0; l < 3; ++l) {
    int K = (l == 0) ? 128 : 256;
    int C = (l == 2) ? 128 : 64;
    int HC = NHEADS * C;
    float* a_s = a_sd + (size_t)l * 2 * N_NODES * NHEADS;
    float* a_d = a_s + (size_t)N_NODES * NHEADS;
    gemm_mfma_kernel<<<dim3(HC / 128, (N_NODES + 127) / 128), 256, 0, stream>>>(
        Acur, Bh[l], Bl[l], h16, asrc[l], adst[l], a_s, a_d, N_NODES, K, HC, C);
    if (l < 2) {
      aggw_kernel<0><<<AGGB, 256, 0, stream>>>(
          h16, a_s, a_d, aec + (size_t)l * TOT * NHEADS, offsets, csr_src, bp[l],
          y16, nullptr);
      Acur = y16;
    } else {
      aggw_kernel<1><<<AGGB, 256, 0, stream>>>(
          h16, a_s, a_d, aec + (size_t)l * TOT * NHEADS, offsets, csr_src, bp[l],
          nullptr, ybuf);
    }
  }
  pool_kernel<<<NB, 128, 0, stream>>>(ybuf, batch, pool, cnt, N_NODES);
  finalize_kernel<<<(8192 + 255) / 256, 256, 0, stream>>>(pool, cnt, (float*)d_out);
}

// Round 10
// 703.744 us; speedup vs baseline: 1.0939x; 1.0939x over previous
//
#include <hip/hip_runtime.h>
#include <hip/hip_bf16.h>
#include <hip/hip_fp16.h>
#include <math.h>

#define N_NODES 50000
#define N_EDGES 800000
#define NHEADS  4
#define NEG_SLOPE 0.2f

typedef __attribute__((ext_vector_type(8))) _Float16 half8v;
typedef __attribute__((ext_vector_type(4))) float f32x4;

__device__ __forceinline__ void gld_lds16(const ushort* g, ushort* l) {
  __builtin_amdgcn_global_load_lds(
      (const __attribute__((address_space(1))) void*)g,
      (__attribute__((address_space(3))) void*)l, 16, 0, 0);
}

__device__ __forceinline__ void fma4(float4& a, uint2 r, float e) {
  __half2 p = *(__half2*)&r.x, q = *(__half2*)&r.y;
  float2 f = __half22float2(p), g2 = __half22float2(q);
  a.x += e * f.x; a.y += e * f.y; a.z += e * g2.x; a.w += e * g2.y;
}

// ---------------------------------------------------------------------------
// fused: fp32->fp16 cast of x  +  split/transpose of all 3 weight matrices
// ---------------------------------------------------------------------------
__global__ void cast_all_kernel(const float* __restrict__ x, __half* __restrict__ x16,
                                const float* __restrict__ W0,
                                const float* __restrict__ W1,
                                const float* __restrict__ W2,
                                __half* __restrict__ B0h, __half* __restrict__ B0l,
                                __half* __restrict__ B1h, __half* __restrict__ B1l,
                                __half* __restrict__ B2h, __half* __restrict__ B2l) {
  int b = blockIdx.x;
  if (b < 6250) {
    int i = b * 256 + threadIdx.x;
    float4 v = ((const float4*)x)[i];
    __half2 a = __floats2half2_rn(v.x, v.y);
    __half2 c = __floats2half2_rn(v.z, v.w);
    ((__half2*)x16)[2 * i] = a;
    ((__half2*)x16)[2 * i + 1] = c;
  } else {
    int i = (b - 6250) * 256 + threadIdx.x;
    if (i >= 229376) return;
    const float* W;
    __half *bh, *bl;
    int kshift, N, base;
    if (i < 32768)       { W = W0; bh = B0h; bl = B0l; kshift = 7; N = 256; base = 0; }
    else if (i < 98304)  { W = W1; bh = B1h; bl = B1l; kshift = 8; N = 256; base = 32768; }
    else                 { W = W2; bh = B2h; bl = B2l; kshift = 8; N = 512; base = 98304; }
    int j = i - base;
    int K = 1 << kshift;
    int nn = j >> kshift, k = j & (K - 1);
    float v = W[(size_t)k * N + nn];
    __half h = __float2half(v);
    bh[j] = h;
    bl[j] = __float2half(v - __half2float(h));
  }
}

// ---------------------------------------------------------------------------
// fp16 split-B MFMA GEMM, 128x128 tile, BK=32, LDS-staged (24 KB).
// ---------------------------------------------------------------------------
__global__ __launch_bounds__(256) void gemm_mfma_kernel(
    const __half* __restrict__ Ah, const __half* __restrict__ Bth,
    const __half* __restrict__ Btl, __half* __restrict__ h16,
    const float* __restrict__ asrc, const float* __restrict__ adst,
    float* __restrict__ a_s, float* __restrict__ a_d, int M, int K, int N, int Cph) {
  __shared__ ushort lds[3 * 4096];
  int tid = threadIdx.x;
  int lane = tid & 63, w = tid >> 6;
  int wm = w >> 1, wn = w & 1;
  int r16 = lane & 15, kgrp = lane >> 4;
  int bm = blockIdx.y * 128, bn = blockIdx.x * 128;

  const ushort* gp[6];
#pragma unroll
  for (int i = 0; i < 6; ++i) {
    int c = i * 256 + tid;
    int mmat = c >> 9;
    int s = c & 511;
    int row = s >> 2;
    int kg = (s & 3) ^ ((row >> 1) & 3);
    const ushort* base;
    int rowg;
    if (mmat == 0)      { base = (const ushort*)Ah;  rowg = min(bm + row, M - 1); }
    else if (mmat == 1) { base = (const ushort*)Bth; rowg = bn + row; }
    else                { base = (const ushort*)Btl; rowg = bn + row; }
    gp[i] = base + (size_t)rowg * K + kg * 8;
  }

  f32x4 acc[4][4] = {};
  for (int k0 = 0; k0 < K; k0 += 32) {
#pragma unroll
    for (int i = 0; i < 6; ++i)
      gld_lds16(gp[i] + k0, lds + i * 2048 + tid * 8);
    __syncthreads();
    half8v ah[4], bh[4], bl[4];
#pragma unroll
    for (int m = 0; m < 4; ++m) {
      int row = wm * 64 + m * 16 + r16;
      int s = row * 4 + (kgrp ^ ((row >> 1) & 3));
      ah[m] = *(const half8v*)(lds + 0 * 4096 + s * 8);
    }
#pragma unroll
    for (int j = 0; j < 4; ++j) {
      int row = wn * 64 + j * 16 + r16;
      int s = row * 4 + (kgrp ^ ((row >> 1) & 3));
      bh[j] = *(const half8v*)(lds + 1 * 4096 + s * 8);
      bl[j] = *(const half8v*)(lds + 2 * 4096 + s * 8);
    }
#pragma unroll
    for (int m = 0; m < 4; ++m)
#pragma unroll
      for (int j = 0; j < 4; ++j) {
        acc[m][j] = __builtin_amdgcn_mfma_f32_16x16x32_f16(ah[m], bh[j], acc[m][j], 0, 0, 0);
        acc[m][j] = __builtin_amdgcn_mfma_f32_16x16x32_f16(ah[m], bl[j], acc[m][j], 0, 0, 0);
      }
    __syncthreads();
  }

  int colbase = bn + wn * 64;
  int hd = colbase / Cph;
#pragma unroll
  for (int m = 0; m < 4; ++m) {
#pragma unroll
    for (int r = 0; r < 4; ++r) {
      int row = bm + wm * 64 + m * 16 + kgrp * 4 + r;
      bool ok = row < M;
      float ps = 0.f, pd = 0.f;
#pragma unroll
      for (int j = 0; j < 4; ++j) {
        float val = acc[m][j][r];
        int col = colbase + 16 * j + r16;
        if (ok) h16[(size_t)row * N + col] = __float2half(val);
        ps += val * asrc[col];
        pd += val * adst[col];
      }
#pragma unroll
      for (int o = 8; o >= 1; o >>= 1) {
        ps += __shfl_xor(ps, o);
        pd += __shfl_xor(pd, o);
      }
      if (r16 == 0 && ok) {
        atomicAdd(&a_s[row * NHEADS + hd], ps);
        atomicAdd(&a_d[row * NHEADS + hd], pd);
      }
    }
  }
}

// ---------------------------------------------------------------------------
// fused: edge_attr column sums (blocks 0..511) + degree count (blocks 512+)
// ---------------------------------------------------------------------------
__global__ void prep0_kernel(const float* __restrict__ ea, float* __restrict__ sums,
                             const int* __restrict__ dst, int* __restrict__ deg, int E) {
  int tid = threadIdx.x;
  if (blockIdx.x < 512) {
    int col = tid & 15;
    float s = 0.f;
    for (int r = blockIdx.x * 16 + (tid >> 4); r < E; r += 512 * 16)
      s += ea[(size_t)r * 16 + col];
    __shared__ float red[256];
    red[tid] = s;
    __syncthreads();
    for (int off = 128; off >= 16; off >>= 1) {
      if (tid < off) red[tid] += red[tid + off];
      __syncthreads();
    }
    if (tid < 16) atomicAdd(&sums[tid], red[tid]);
  } else {
    int i = (blockIdx.x - 512) * 256 + tid;
    int s = 2048 * 256;
    for (; i < E; i += s) atomicAdd(&deg[dst[i]], 1);
  }
}

// ---------------------------------------------------------------------------
// wvec + ae_self
// ---------------------------------------------------------------------------
__global__ void wvec_kernel(const float* __restrict__ We0, const float* __restrict__ ae0,
                            const float* __restrict__ We1, const float* __restrict__ ae1,
                            const float* __restrict__ We2, const float* __restrict__ ae2,
                            const float* __restrict__ ea_sum,
                            float* __restrict__ wvec, float* __restrict__ ae_self) {
  __shared__ float sw[192];
  int tid = threadIdx.x;
  if (tid < 192) {
    int l = tid >> 6, rem = tid & 63, k = rem >> 2, hd = rem & 3;
    int C = (l == 2) ? 128 : 64;
    const float* We = (l == 0) ? We0 : (l == 1) ? We1 : We2;
    const float* ae = (l == 0) ? ae0 : (l == 1) ? ae1 : ae2;
    float s = 0.f;
    for (int c = 0; c < C; ++c) s += We[(size_t)k * (4 * C) + hd * C + c] * ae[hd * C + c];
    sw[tid] = s;
    wvec[tid] = s;
  }
  __syncthreads();
  if (tid < 12) {
    int l = tid >> 2, hd = tid & 3;
    const float invE = 1.0f / (float)N_EDGES;
    float s = 0.f;
    for (int k = 0; k < 16; ++k) s += ea_sum[k] * invE * sw[l * 64 + k * 4 + hd];
    ae_self[tid] = s;
  }
}

// ---------------------------------------------------------------------------
// CSR build: hierarchical scan + packed scatter
// ---------------------------------------------------------------------------
__global__ void scan_a_kernel(const int* __restrict__ deg, int* __restrict__ tmp,
                              int* __restrict__ bsum, int n) {
  __shared__ int s[256];
  int i = blockIdx.x * 256 + threadIdx.x;
  int v = (i < n) ? (deg[i] + 1) : 0;
  s[threadIdx.x] = v;
  __syncthreads();
  for (int d = 1; d < 256; d <<= 1) {
    int t = (threadIdx.x >= d) ? s[threadIdx.x - d] : 0;
    __syncthreads();
    s[threadIdx.x] += t;
    __syncthreads();
  }
  if (i < n) tmp[i] = s[threadIdx.x] - v;
  if (threadIdx.x == 255) bsum[blockIdx.x] = s[255];
}
__global__ void scan_b_kernel(int* bsum, int nb) {
  __shared__ int s[256];
  int v = (threadIdx.x < nb) ? bsum[threadIdx.x] : 0;
  s[threadIdx.x] = v;
  __syncthreads();
  for (int d = 1; d < 256; d <<= 1) {
    int t = (threadIdx.x >= d) ? s[threadIdx.x - d] : 0;
    __syncthreads();
    s[threadIdx.x] += t;
    __syncthreads();
  }
  if (threadIdx.x < nb) bsum[threadIdx.x] = s[threadIdx.x] - v;
}
__global__ void scan_c_kernel(const int* __restrict__ tmp, const int* __restrict__ bsum,
                              int* __restrict__ offsets, int* __restrict__ cursor,
                              int n, int tot) {
  int i = blockIdx.x * 256 + threadIdx.x;
  if (i < n) {
    int o = tmp[i] + bsum[blockIdx.x];
    offsets[i] = o;
    cursor[i] = o;
  }
  if (i == 0) offsets[n] = tot;
}
__global__ void scatter_kernel(const int* __restrict__ src, const int* __restrict__ dst,
                               int* cursor, uint2* __restrict__ csr_pack, int E, int n) {
  int i = blockIdx.x * blockDim.x + threadIdx.x;
  int s = gridDim.x * blockDim.x;
  int tot = E + n;
  for (; i < tot; i += s) {
    int ss, dd, eid;
    if (i < E) { ss = src[i]; dd = dst[i]; eid = i; }
    else       { ss = i - E; dd = ss;     eid = E; }
    int pos = atomicAdd(&cursor[dd], 1);
    csr_pack[pos] = make_uint2((uint)ss, (uint)eid);
  }
}

// ---------------------------------------------------------------------------
// a_e in CSR order for all 3 layers + csr_src unpack
// ---------------------------------------------------------------------------
__global__ void ae_csr_kernel(const float* __restrict__ ea, const float* __restrict__ wv,
                              const float* __restrict__ ae_self,
                              const uint2* __restrict__ csr_pack,
                              float* __restrict__ aec, int* __restrict__ csr_src,
                              int tot, int E) {
  int i = blockIdx.x * blockDim.x + threadIdx.x;
  int stride = gridDim.x * blockDim.x;
  for (int p = i; p < tot; p += stride) {
    uint2 pk = csr_pack[p];
    int eid = (int)pk.y;
    csr_src[p] = (int)pk.x;
    if (eid >= E) {
#pragma unroll
      for (int l = 0; l < 3; ++l)
        *(float4*)(aec + ((size_t)l * tot + p) * 4) =
            make_float4(ae_self[l * 4 + 0], ae_self[l * 4 + 1],
                        ae_self[l * 4 + 2], ae_self[l * 4 + 3]);
    } else {
      float row[16];
      const float4* rp = (const float4*)(ea + (size_t)eid * 16);
#pragma unroll
      for (int q = 0; q < 4; ++q) {
        float4 v = rp[q];
        row[q * 4 + 0] = v.x; row[q * 4 + 1] = v.y;
        row[q * 4 + 2] = v.z; row[q * 4 + 3] = v.w;
      }
#pragma unroll
      for (int l = 0; l < 3; ++l) {
        float s0 = 0, s1 = 0, s2 = 0, s3 = 0;
#pragma unroll
        for (int k = 0; k < 16; ++k) {
          float v = row[k];
          s0 += v * wv[l * 64 + k * 4 + 0];
          s1 += v * wv[l * 64 + k * 4 + 1];
          s2 += v * wv[l * 64 + k * 4 + 2];
          s3 += v * wv[l * 64 + k * 4 + 3];
        }
        *(float4*)(aec + ((size_t)l * tot + p) * 4) = make_float4(s0, s1, s2, s3);
      }
    }
  }
}

// ---------------------------------------------------------------------------
// aggregation, NPB=2 nodes per block, stage-batched for MLP.
// MODE 0 -> fp16 y (next layer's A);  MODE 1 -> head-mean fp32 to ybuf
// ---------------------------------------------------------------------------
template <int C, int MODE>
__global__ __launch_bounds__(256) void agg_kernel(
    const __half* __restrict__ h, const float* __restrict__ a_s,
    const float* __restrict__ a_d, const float* __restrict__ a_e,
    const int* __restrict__ offsets, const int* __restrict__ csr_src,
    const float* __restrict__ bias, __half* __restrict__ y16,
    float* __restrict__ yf) {
  constexpr int NPB = 2;
  constexpr int HC = NHEADS * C;   // 256 or 512
  constexpr int SL = HC / 4;       // 64 or 128
  constexpr int G = 256 / SL;      // 4 or 2
  constexpr int HSH = (C == 64) ? 4 : 5;

  __shared__ float exbuf[NPB][NHEADS][64];
  __shared__ int sbuf[NPB][64];
  __shared__ float dshare[NPB][NHEADS];
  __shared__ float4 cbuf4[NPB][(C == 64) ? 192 : 128];

  int tid = threadIdx.x;
  int hd = tid >> 6, l = tid & 63;
  int i = tid & (SL - 1);
  int g = tid / SL;
  int hh = i >> HSH;
  int nbase = blockIdx.x * NPB;

  int beg[NPB], deg[NPB];
  bool fast[NPB];
#pragma unroll
  for (int it = 0; it < NPB; ++it) {
    int nd = nbase + it;
    if (nd < N_NODES) {
      int b0 = offsets[nd];
      beg[it] = b0;
      deg[it] = offsets[nd + 1] - b0;
    } else { beg[it] = 0; deg[it] = 0; }
    fast[it] = (deg[it] <= 64);
  }

  // ---- stage A: softmax for fast nodes ----
#pragma unroll
  for (int it = 0; it < NPB; ++it) {
    if (!fast[it]) continue;
    int nd = nbase + it;
    bool valid = l < deg[it];
    float a_dn = (nd < N_NODES) ? a_d[nd * NHEADS + hd] : 0.f;
    int s = 0;
    float al = -1e30f;
    if (valid) {
      int j = beg[it] + l;
      s = csr_src[j];
      float aev = a_e[(size_t)j * NHEADS + hd];
      float v = a_s[s * NHEADS + hd] + a_dn + aev;
      al = (v > 0.f) ? v : NEG_SLOPE * v;
    }
    float m = al;
#pragma unroll
    for (int o = 32; o >= 1; o >>= 1) m = fmaxf(m, __shfl_xor(m, o));
    float ex = valid ? __expf(al - m) : 0.f;
    float ds = ex;
#pragma unroll
    for (int o = 32; o >= 1; o >>= 1) ds += __shfl_xor(ds, o);
    exbuf[it][hd][l] = ex;
    if (hd == 0) sbuf[it][l] = s;
    if (l == 0) dshare[it][hd] = ds;
  }
  __syncthreads();

  // ---- stage B: gather-accumulate ----
  float4 acc[NPB];
#pragma unroll
  for (int it = 0; it < NPB; ++it) acc[it] = make_float4(0.f, 0.f, 0.f, 0.f);

  auto accum = [&](int it, float4& a) {
    int cnt_e = deg[it];
    int t = g;
    for (; t + 3 * G < cnt_e; t += 4 * G) {
      int s0 = sbuf[it][t], s1 = sbuf[it][t + G];
      int s2 = sbuf[it][t + 2 * G], s3 = sbuf[it][t + 3 * G];
      float e0 = exbuf[it][hh][t], e1 = exbuf[it][hh][t + G];
      float e2 = exbuf[it][hh][t + 2 * G], e3 = exbuf[it][hh][t + 3 * G];
      uint2 r0 = *(const uint2*)(h + (size_t)s0 * HC + 4 * i);
      uint2 r1 = *(const uint2*)(h + (size_t)s1 * HC + 4 * i);
      uint2 r2 = *(const uint2*)(h + (size_t)s2 * HC + 4 * i);
      uint2 r3 = *(const uint2*)(h + (size_t)s3 * HC + 4 * i);
      fma4(a, r0, e0); fma4(a, r1, e1); fma4(a, r2, e2); fma4(a, r3, e3);
    }
    for (; t < cnt_e; t += G) {
      int s0 = sbuf[it][t];
      float e0 = exbuf[it][hh][t];
      uint2 r0 = *(const uint2*)(h + (size_t)s0 * HC + 4 * i);
      fma4(a, r0, e0);
    }
  };
#pragma unroll
  for (int it = 0; it < NPB; ++it)
    if (fast[it]) accum(it, acc[it]);

  // ---- stage C/D: epilogues ----
  if (MODE == 0) {
#pragma unroll
    for (int it = 0; it < NPB; ++it)
      if (fast[it] && g > 0) cbuf4[it][(g - 1) * SL + i] = acc[it];
    __syncthreads();
    if (g == 0) {
#pragma unroll
      for (int it = 0; it < NPB; ++it) {
        int nd = nbase + it;
        if (!fast[it] || nd >= N_NODES) continue;
        float4 c1 = cbuf4[it][i], c2 = cbuf4[it][SL + i], c3 = cbuf4[it][2 * SL + i];
        float4 a = acc[it];
        a.x += c1.x + c2.x + c3.x;
        a.y += c1.y + c2.y + c3.y;
        a.z += c1.z + c2.z + c3.z;
        a.w += c1.w + c2.w + c3.w;
        float inv = 1.f / (dshare[it][hh] + 1e-16f);
        const float4 bv = *(const float4*)(bias + 4 * i);
        float o0 = a.x * inv + bv.x, o1 = a.y * inv + bv.y;
        float o2 = a.z * inv + bv.z, o3 = a.w * inv + bv.w;
        o0 = (o0 > 0.f) ? o0 : (__expf(o0) - 1.f);
        o1 = (o1 > 0.f) ? o1 : (__expf(o1) - 1.f);
        o2 = (o2 > 0.f) ? o2 : (__expf(o2) - 1.f);
        o3 = (o3 > 0.f) ? o3 : (__expf(o3) - 1.f);
        __half2 w0 = __floats2half2_rn(o0, o1);
        __half2 w1 = __floats2half2_rn(o2, o3);
        uint2 pk;
        pk.x = *(uint*)&w0;
        pk.y = *(uint*)&w1;
        *(uint2*)(y16 + (size_t)nd * HC + 4 * i) = pk;
      }
    }
  } else {  // MODE 1: head-mean -> fp32 yf (coalesced)
#pragma unroll
    for (int it = 0; it < NPB; ++it)
      if (fast[it] && g == 1) cbuf4[it][i] = acc[it];
    __syncthreads();
    if (g == 0) {
#pragma unroll
      for (int it = 0; it < NPB; ++it) {
        if (!fast[it]) continue;
        float4 c1 = cbuf4[it][i];
        float inv = 1.f / (dshare[it][hh] + 1e-16f);
        float4 v;
        v.x = (acc[it].x + c1.x) * inv;
        v.y = (acc[it].y + c1.y) * inv;
        v.z = (acc[it].z + c1.z) * inv;
        v.w = (acc[it].w + c1.w) * inv;
        cbuf4[it][i] = v;
      }
    }
    __syncthreads();
    {
      int it2 = tid >> 5, l32 = tid & 31;
      if (it2 < NPB) {
        int nd = nbase + it2;
        if (fast[it2] && nd < N_NODES) {
          float4 s0 = cbuf4[it2][l32], s1 = cbuf4[it2][l32 + 32];
          float4 s2 = cbuf4[it2][l32 + 64], s3 = cbuf4[it2][l32 + 96];
          const float4 bv = *(const float4*)(bias + 4 * l32);
          float4 o;
          o.x = (s0.x + s1.x + s2.x + s3.x) * 0.25f + bv.x;
          o.y = (s0.y + s1.y + s2.y + s3.y) * 0.25f + bv.y;
          o.z = (s0.z + s1.z + s2.z + s3.z) * 0.25f + bv.z;
          o.w = (s0.w + s1.w + s2.w + s3.w) * 0.25f + bv.w;
          *(float4*)(yf + (size_t)nd * 128 + 4 * l32) = o;
        }
      }
    }
  }

  // ---- deferred slow path (deg > 64), rare ----
  bool any_slow = false;
#pragma unroll
  for (int it = 0; it < NPB; ++it) any_slow |= !fast[it];
  if (!any_slow) return;
  __syncthreads();

  for (int it = 0; it < NPB; ++it) {
    if (fast[it]) continue;
    int nd = nbase + it;
    int b0 = beg[it], end = b0 + deg[it];
    float a_dn = a_d[nd * NHEADS + hd];
    float m = -1e30f;
    for (int j0 = b0; j0 < end; j0 += 64) {
      int j = j0 + l;
      if (j < end) {
        int s = csr_src[j];
        float aev = a_e[(size_t)j * NHEADS + hd];
        float v = a_s[s * NHEADS + hd] + a_dn + aev;
        float al = (v > 0.f) ? v : NEG_SLOPE * v;
        m = fmaxf(m, al);
      }
    }
#pragma unroll
    for (int o = 32; o >= 1; o >>= 1) m = fmaxf(m, __shfl_xor(m, o));
    float dsum = 0.f;
    float4 sacc = make_float4(0.f, 0.f, 0.f, 0.f);
    for (int j0 = b0; j0 < end; j0 += 64) {
      int j = j0 + l;
      int cnt_e = min(64, end - j0);
      float ex = 0.f;
      int s = 0;
      if (j < end) {
        s = csr_src[j];
        float aev = a_e[(size_t)j * NHEADS + hd];
        float v = a_s[s * NHEADS + hd] + a_dn + aev;
        float al = (v > 0.f) ? v : NEG_SLOPE * v;
        ex = __expf(al - m);
      }
      dsum += ex;
      __syncthreads();
      exbuf[0][hd][l] = ex;
      if (hd == 0) sbuf[0][l] = s;
      __syncthreads();
      {
        int t = g;
        for (; t < cnt_e; t += G) {
          int s0 = sbuf[0][t];
          float e0 = exbuf[0][hh][t];
          uint2 r0 = *(const uint2*)(h + (size_t)s0 * HC + 4 * i);
          fma4(sacc, r0, e0);
        }
      }
    }
#pragma unroll
    for (int o = 32; o >= 1; o >>= 1) dsum += __shfl_xor(dsum, o);
    if (l == 0) dshare[0][hd] = dsum;
    __syncthreads();

    if (MODE == 0) {
      if (g > 0) cbuf4[0][(g - 1) * SL + i] = sacc;
      __syncthreads();
      if (g == 0) {
        float4 c1 = cbuf4[0][i], c2 = cbuf4[0][SL + i], c3 = cbuf4[0][2 * SL + i];
        sacc.x += c1.x + c2.x + c3.x;
        sacc.y += c1.y + c2.y + c3.y;
        sacc.z += c1.z + c2.z + c3.z;
        sacc.w += c1.w + c2.w + c3.w;
        float inv = 1.f / (dshare[0][hh] + 1e-16f);
        const float4 bv = *(const float4*)(bias + 4 * i);
        float o0 = sacc.x * inv + bv.x, o1 = sacc.y * inv + bv.y;
        float o2 = sacc.z * inv + bv.z, o3 = sacc.w * inv + bv.w;
        o0 = (o0 > 0.f) ? o0 : (__expf(o0) - 1.f);
        o1 = (o1 > 0.f) ? o1 : (__expf(o1) - 1.f);
        o2 = (o2 > 0.f) ? o2 : (__expf(o2) - 1.f);
        o3 = (o3 > 0.f) ? o3 : (__expf(o3) - 1.f);
        __half2 w0 = __floats2half2_rn(o0, o1);
        __half2 w1 = __floats2half2_rn(o2, o3);
        uint2 pk;
        pk.x = *(uint*)&w0;
        pk.y = *(uint*)&w1;
        *(uint2*)(y16 + (size_t)nd * HC + 4 * i) = pk;
      }
      __syncthreads();
    } else {
      if (g == 1) cbuf4[0][i] = sacc;
      __syncthreads();
      if (g == 0) {
        float4 c1 = cbuf4[0][i];
        float inv = 1.f / (dshare[0][hh] + 1e-16f);
        float4 v;
        v.x = (sacc.x + c1.x) * inv;
        v.y = (sacc.y + c1.y) * inv;
        v.z = (sacc.z + c1.z) * inv;
        v.w = (sacc.w + c1.w) * inv;
        cbuf4[0][i] = v;
      }
      __syncthreads();
      if (tid < 32) {
        float4 s0 = cbuf4[0][tid], s1 = cbuf4[0][tid + 32];
        float4 s2 = cbuf4[0][tid + 64], s3 = cbuf4[0][tid + 96];
        const float4 bv = *(const float4*)(bias + 4 * tid);
        float4 o;
        o.x = (s0.x + s1.x + s2.x + s3.x) * 0.25f + bv.x;
        o.y = (s0.y + s1.y + s2.y + s3.y) * 0.25f + bv.y;
        o.z = (s0.z + s1.z + s2.z + s3.z) * 0.25f + bv.z;
        o.w = (s0.w + s1.w + s2.w + s3.w) * 0.25f + bv.w;
        *(float4*)(yf + (size_t)nd * 128 + 4 * tid) = o;
      }
      __syncthreads();
    }
  }
}

// ---------------------------------------------------------------------------
// global mean pool (segment-batched over sorted batch ids)
// ---------------------------------------------------------------------------
__global__ void pool_kernel(const float* __restrict__ y, const int* __restrict__ batch,
                            float* __restrict__ pool, float* __restrict__ cnt, int n) {
  int n0 = blockIdx.x * 256;
  if (n0 >= n) return;
  int n1 = min(n0 + 256, n);
  int c = threadIdx.x;  // 128 threads
  float accum = 0.f;
  int cur = batch[n0];
  int cn = 0;
  for (int nd = n0; nd < n1; ++nd) {
    int g = batch[nd];
    if (g != cur) {
      atomicAdd(&pool[cur * 128 + c], accum);
      if (c == 0) atomicAdd(&cnt[cur], (float)cn);
      accum = 0.f; cn = 0; cur = g;
    }
    accum += y[(size_t)nd * 128 + c];
    cn++;
  }
  atomicAdd(&pool[cur * 128 + c], accum);
  if (c == 0) atomicAdd(&cnt[cur], (float)cn);
}
__global__ void finalize_kernel(const float* __restrict__ pool,
                                const float* __restrict__ cnt, float* __restrict__ out) {
  int i = blockIdx.x * blockDim.x + threadIdx.x;
  if (i < 64 * 128) out[i] = pool[i] / fmaxf(cnt[i >> 7], 1.f);
}

// ---------------------------------------------------------------------------
extern "C" void kernel_launch(void* const* d_in, const int* in_sizes, int n_in,
                              void* d_out, int out_size, void* d_ws, size_t ws_size,
                              hipStream_t stream) {
  const float* x = (const float*)d_in[0];
  const int* ei = (const int*)d_in[1];
  const float* ea = (const float*)d_in[2];
  const int* batch = (const int*)d_in[3];
  const float* W[3]    = {(const float*)d_in[4],  (const float*)d_in[10], (const float*)d_in[16]};
  const float* asrc[3] = {(const float*)d_in[5],  (const float*)d_in[11], (const float*)d_in[17]};
  const float* adst[3] = {(const float*)d_in[6],  (const float*)d_in[12], (const float*)d_in[18]};
  const float* Wep[3]  = {(const float*)d_in[7],  (const float*)d_in[13], (const float*)d_in[19]};
  const float* aep[3]  = {(const float*)d_in[8],  (const float*)d_in[14], (const float*)d_in[20]};
  const float* bp[3]   = {(const float*)d_in[9],  (const float*)d_in[15], (const float*)d_in[21]};

  char* ws = (char*)d_ws;
  size_t off = 0;
  auto take = [&](size_t bytes) -> void* {
    void* p = ws + off;
    off = (off + bytes + 255) & ~(size_t)255;
    return p;
  };
  const int TOT = N_EDGES + N_NODES;
  size_t zero_begin = off;
  float* ea_sum = (float*)take(16 * 4);
  float* pool   = (float*)take(8192 * 4);
  float* cnt    = (float*)take(64 * 4);
  int*   deg    = (int*)take((size_t)N_NODES * 4);
  float* a_sd   = (float*)take((size_t)3 * 2 * N_NODES * NHEADS * 4);
  size_t zero_bytes = off - zero_begin;

  float* wvec    = (float*)take(192 * 4);
  float* ae_self = (float*)take(12 * 4);
  int* tmp     = (int*)take((size_t)N_NODES * 4);
  int* bsum    = (int*)take(256 * 4);
  int* offsets = (int*)take(((size_t)N_NODES + 1) * 4);
  int* cursor  = (int*)take((size_t)N_NODES * 4);
  uint2* csr_pack = (uint2*)take((size_t)TOT * 8);
  int* csr_src = (int*)take((size_t)TOT * 4);
  float* aec  = (float*)take((size_t)3 * TOT * NHEADS * 4);
  __half* x16 = (__half*)take((size_t)N_NODES * 128 * 2);
  __half* Bh[3], *Bl[3];
  Bh[0] = (__half*)take((size_t)32768 * 2);  Bl[0] = (__half*)take((size_t)32768 * 2);
  Bh[1] = (__half*)take((size_t)65536 * 2);  Bl[1] = (__half*)take((size_t)65536 * 2);
  Bh[2] = (__half*)take((size_t)131072 * 2); Bl[2] = (__half*)take((size_t)131072 * 2);
  __half* h16 = (__half*)take((size_t)N_NODES * 512 * 2);
  __half* y16 = (__half*)take((size_t)N_NODES * 256 * 2);
  float* ybuf = (float*)take((size_t)N_NODES * 128 * 4);

  const int* srcp = ei;
  const int* dstp = ei + N_EDGES;
  const int NB = (N_NODES + 255) / 256;

  hipMemsetAsync(ws + zero_begin, 0, zero_bytes, stream);
  prep0_kernel<<<512 + 2048, 256, 0, stream>>>(ea, ea_sum, dstp, deg, N_EDGES);
  scan_a_kernel<<<NB, 256, 0, stream>>>(deg, tmp, bsum, N_NODES);
  scan_b_kernel<<<1, 256, 0, stream>>>(bsum, NB);
  scan_c_kernel<<<NB, 256, 0, stream>>>(tmp, bsum, offsets, cursor, N_NODES, TOT);
  scatter_kernel<<<2048, 256, 0, stream>>>(srcp, dstp, cursor, csr_pack, N_EDGES, N_NODES);
  wvec_kernel<<<1, 256, 0, stream>>>(Wep[0], aep[0], Wep[1], aep[1], Wep[2], aep[2],
                                     ea_sum, wvec, ae_self);
  ae_csr_kernel<<<2048, 256, 0, stream>>>(ea, wvec, ae_self, csr_pack, aec, csr_src,
                                          TOT, N_EDGES);
  cast_all_kernel<<<6250 + 896, 256, 0, stream>>>(x, x16, W[0], W[1], W[2], Bh[0], Bl[0],
                                                  Bh[1], Bl[1], Bh[2], Bl[2]);

  const __half* Acur = x16;
  const int AGGB = (N_NODES + 1) / 2;
  for (int l = 0; l < 3; ++l) {
    int K = (l == 0) ? 128 : 256;
    int C = (l == 2) ? 128 : 64;
    int HC = NHEADS * C;
    float* a_s = a_sd + (size_t)l * 2 * N_NODES * NHEADS;
    float* a_d = a_s + (size_t)N_NODES * NHEADS;
    gemm_mfma_kernel<<<dim3(HC / 128, (N_NODES + 127) / 128), 256, 0, stream>>>(
        Acur, Bh[l], Bl[l], h16, asrc[l], adst[l], a_s, a_d, N_NODES, K, HC, C);
    if (l < 2) {
      agg_kernel<64, 0><<<AGGB, 256, 0, stream>>>(
          h16, a_s, a_d, aec + (size_t)l * TOT * NHEADS, offsets, csr_src, bp[l],
          y16, nullptr);
      Acur = y16;
    } else {
      agg_kernel<128, 1><<<AGGB, 256, 0, stream>>>(
          h16, a_s, a_d, aec + (size_t)l * TOT * NHEADS, offsets, csr_src, bp[l],
          nullptr, ybuf);
    }
  }
  pool_kernel<<<NB, 128, 0, stream>>>(ybuf, batch, pool, cnt, N_NODES);
  finalize_kernel<<<(8192 + 255) / 256, 256, 0, stream>>>(pool, cnt, (float*)d_out);
}